// Round 3
// baseline (443.572 us; speedup 1.0000x reference)
//
#include <hip/hip_runtime.h>

typedef unsigned int u32;
typedef unsigned short u16;
typedef short bf16x8 __attribute__((ext_vector_type(8)));
typedef float f32x4 __attribute__((ext_vector_type(4)));

#define KOFF 27

__device__ __forceinline__ float bf2f(u16 u) {
    u32 x = ((u32)u) << 16;
    return __builtin_bit_cast(float, x);
}
__device__ __forceinline__ u16 f2bf(float f) {
    u32 u = __builtin_bit_cast(u32, f);
    u32 r = (u + 0x7FFFu + ((u >> 16) & 1u)) >> 16;  // RNE
    return (u16)r;
}
__device__ __forceinline__ void async16(void* lds, const void* g) {
    __builtin_amdgcn_global_load_lds(
        (const __attribute__((address_space(1))) u32*)g,
        (__attribute__((address_space(3))) u32*)lds, 16, 0, 0);
}

// ---------------------------------------------------------------------------
// Mega prep: all weight transposes + head tables in ONE launch.
//  blocks 0..539  : 10 conv weights, W[k][c][d] f32 -> bf16 Wt[k][d][c^sw]
//  blocks 540..543: h0W1/h1W1 -> Wt2[256][128] bf16 swizzled (head L1 concat)
//  blocks 544..545: h0W2/h1W2 [128][16] f32 -> wt2h [2][16][128] bf16 swizzled
//  blocks 546..553: E1[16][128] = s1emb @ h1W1 (fp32, exact)
// ---------------------------------------------------------------------------
struct PrepArgs {
    const float* ws[12];  // 10 conv W + h0W1 + h1W1
    u16* wd[12];          // 10 conv Wt + Wt2 rows 0..127 + Wt2 rows 128..255
    const float* h0W2;
    const float* h1W2;
    u16* wt2h;
    const float* s1emb;
    const float* h1W1f;
    float* E1;
};
__global__ __launch_bounds__(256) void prep_mega(PrepArgs a) {
    __shared__ float t[128][65];
    const int bid = blockIdx.x;
    if (bid < 544) {
        int w, k, half;
        if (bid < 540) {
            w = bid / 54;
            int r = bid % 54;
            k = r >> 1;
            half = r & 1;
        } else {
            int r = bid - 540;
            w = 10 + (r >> 1);
            k = 0;
            half = r & 1;
        }
        const float* s = a.ws[w] + k * 16384 + half * 64;
        for (int i = threadIdx.x; i < 8192; i += 256) {
            int c = i >> 6, dl = i & 63;
            t[c][dl] = s[c * 128 + dl];
        }
        __syncthreads();
        u16* db = a.wd[w] + k * 16384;
        for (int i = threadIdx.x; i < 8192; i += 256) {
            int dl = i >> 7, c = i & 127;
            int d = half * 64 + dl;
            db[d * 128 + (c ^ ((d & 7) << 3))] = f2bf(t[c][dl]);
        }
    } else if (bid < 546) {
        int h = bid - 544;
        const float* src = h ? a.h1W2 : a.h0W2;
        u16* dst = a.wt2h + h * 2048;
        for (int i = threadIdx.x; i < 2048; i += 256) {
            int j = i >> 7, d = i & 127;
            dst[j * 128 + (d ^ ((j & 7) << 3))] = f2bf(src[d * 16 + j]);
        }
    } else {
        int b = bid - 546;  // 0..7
        int r = b * 2 + (threadIdx.x >> 7);
        int c = threadIdx.x & 127;
        float acc = 0.f;
        for (int kx = 0; kx < 128; ++kx)
            acc = fmaf(a.s1emb[r * 128 + kx], a.h1W1f[kx * 128 + c], acc);
        a.E1[r * 128 + c] = acc;
    }
}

// f0[n][c] = prior_emb[x_O[n]][c]  (fp32 -> bf16)
__global__ __launch_bounds__(256) void embed_k(const int* __restrict__ xO,
                                               const float* __restrict__ emb,
                                               u16* __restrict__ out) {
    int idx = blockIdx.x * 256 + threadIdx.x;
    int c = idx & 127, n = idx >> 7;
    out[idx] = f2bf(emb[xO[n] * 128 + c]);
}

// g[m][c] = f[m>>3][c] + oct_emb[child_oct[m]][c]
__global__ __launch_bounds__(256) void expand_k(const u16* __restrict__ f,
                                                const int* __restrict__ oct,
                                                const float* __restrict__ oemb,
                                                u16* __restrict__ g) {
    int idx = blockIdx.x * 256 + threadIdx.x;
    int c = idx & 127, m = idx >> 7;
    g[idx] = f2bf(bf2f(f[(m >> 3) * 128 + c]) + oemb[oct[m] * 128 + c]);
}

// ---------------------------------------------------------------------------
// Pipelined sparse conv, BM points/block, 512 threads (8 waves).
// Double-buffered A (gathered) + B (pre-swizzled weights) in LDS; counted
// s_waitcnt vmcnt(N) so next offset's loads stay in flight across barriers.
// Swizzle: byte-in-row ^= (row&7)<<4 on both the staged source and the read.
// BM=128: wave = 32x64 (MR=2,NR=4);  BM=32: wave = 16x32 (MR=1,NR=2).
// ---------------------------------------------------------------------------
template <int BM>
__global__ __launch_bounds__(512, 1) void conv_pipe(
    const u16* __restrict__ fin, const int* __restrict__ nbr,
    const u16* __restrict__ wt, const u16* __restrict__ res,
    u16* __restrict__ fout) {
    constexpr int MR = BM == 128 ? 2 : 1;
    constexpr int NR = BM == 128 ? 4 : 2;
    __shared__ __align__(16) u16 Asb[2][BM * 128];
    __shared__ __align__(16) u16 Bsb[2][128 * 128];
    __shared__ int nbrS[BM * KOFF];
    const int tid = threadIdx.x;
    const int wid = tid >> 6;
    const int lane = tid & 63;
    const int p0 = blockIdx.x * BM;

    for (int i = tid; i < BM * KOFF; i += 512)
        nbrS[i] = nbr[(p0 + i / KOFF) * KOFF + (i % KOFF)];
    __syncthreads();  // full drain: vmcnt==0 past this point

    f32x4 acc[MR][NR];
#pragma unroll
    for (int m = 0; m < MR; ++m)
#pragma unroll
        for (int n = 0; n < NR; ++n) acc[m][n] = f32x4{0.f, 0.f, 0.f, 0.f};

    const int RB = BM == 128 ? (wid >> 1) * 32 : (wid >> 2) * 16;
    const int CB = BM == 128 ? (wid & 1) * 64 : (wid & 3) * 32;
    const int lrow = lane & 15;
    const int lkb = (lane >> 4) * 16;

    auto stage = [&](int k, int buf) {
#pragma unroll
        for (int i = 0; i < BM / 32; ++i) {
            int o = i * 8192 + tid * 16;
            int r = o >> 8;
            int cbs = (o & 255) ^ ((r & 7) << 4);
            int rg = nbrS[r * KOFF + k];
            async16((char*)&Asb[buf][0] + i * 8192 + wid * 1024,
                    (const char*)fin + (size_t)rg * 256 + cbs);
        }
        const char* wk = (const char*)wt + k * 32768;
#pragma unroll
        for (int i = 0; i < 4; ++i)
            async16((char*)&Bsb[buf][0] + i * 8192 + wid * 1024,
                    wk + i * 8192 + tid * 16);
    };

    stage(0, 0);
    int cur = 0;
#pragma unroll 1
    for (int k = 0; k < KOFF; ++k) {
        if (k + 1 < KOFF) {
            stage(k + 1, cur ^ 1);
            if constexpr (BM == 128)
                asm volatile("s_waitcnt vmcnt(8)" ::: "memory");
            else
                asm volatile("s_waitcnt vmcnt(5)" ::: "memory");
        } else {
            asm volatile("s_waitcnt vmcnt(0)" ::: "memory");
        }
        __builtin_amdgcn_s_barrier();       // all waves' cur loads done
        __builtin_amdgcn_sched_barrier(0);  // no ds_read hoisting above
        __builtin_amdgcn_s_setprio(1);
#pragma unroll
        for (int kk = 0; kk < 4; ++kk) {
            bf16x8 av[MR], bv[NR];
#pragma unroll
            for (int m = 0; m < MR; ++m) {
                int row = RB + m * 16 + lrow;
                int cb = (kk * 64 + lkb) ^ ((row & 7) << 4);
                av[m] = *(const bf16x8*)((const char*)&Asb[cur][0] + row * 256 + cb);
            }
#pragma unroll
            for (int n = 0; n < NR; ++n) {
                int drow = CB + n * 16 + lrow;
                int cb = (kk * 64 + lkb) ^ ((drow & 7) << 4);
                bv[n] = *(const bf16x8*)((const char*)&Bsb[cur][0] + drow * 256 + cb);
            }
#pragma unroll
            for (int m = 0; m < MR; ++m)
#pragma unroll
                for (int n = 0; n < NR; ++n)
                    acc[m][n] = __builtin_amdgcn_mfma_f32_16x16x32_bf16(
                        av[m], bv[n], acc[m][n], 0, 0, 0);
        }
        __builtin_amdgcn_s_setprio(0);
        __builtin_amdgcn_s_barrier();  // all waves done reading cur
        cur ^= 1;
    }

    // epilogue: (+res), relu, bf16.  D layout: col=lane&15, row=(lane>>4)*4+q
#pragma unroll
    for (int m = 0; m < MR; ++m) {
        int prow = p0 + RB + m * 16 + (lane >> 4) * 4;
#pragma unroll
        for (int n = 0; n < NR; ++n) {
            int dcol = CB + n * 16 + lrow;
#pragma unroll
            for (int q = 0; q < 4; ++q) {
                float v = acc[m][n][q];
                int p = prow + q;
                if (res) v += bf2f(res[p * 128 + dcol]);
                v = v > 0.f ? v : 0.f;
                fout[p * 128 + dcol] = f2bf(v);
            }
        }
    }
}

// ---------------------------------------------------------------------------
// Fused heads: one block = 128 points.
//  MFMA1: Hcat[128][256] = relu(G@[W1a|W1b] + b1 (+E1[gt0] for head1 cols))
//  MFMA2: logits[128][16] per head from Hcat (LDS) x W2t (LDS)
//  softmax over 16 lanes + gathered -log2 + per-block partial sum.
// LDS: A(32K)+B(64K) staged; H(64K) aliases them after MFMA1.
// ---------------------------------------------------------------------------
__global__ __launch_bounds__(512, 1) void fused_heads(
    const u16* __restrict__ G, const int* __restrict__ gtO,
    const u16* __restrict__ wt2, const u16* __restrict__ wt2h,
    const float* __restrict__ b1a, const float* __restrict__ b1b,
    const float* __restrict__ E1, const float* __restrict__ b2a,
    const float* __restrict__ b2b, float* __restrict__ partial) {
    __shared__ __align__(16) u16 AB[49152];   // 96KB: A 32K | B 64K
    __shared__ __align__(16) u16 W2ts[4096];  // 8KB: [2][16][128] swizzled
    __shared__ float E1s[2048];
    __shared__ float b2s[32];
    __shared__ int gts[256];
    __shared__ float bitsS[256];
    u16* Asb = AB;
    u16* Bsb = AB + 16384;
    char* Hb = (char*)AB;  // 128 rows x 512B, aliases A+B (dead after MFMA1)
    const int tid = threadIdx.x, wid = tid >> 6, lane = tid & 63;
    const int lrow = lane & 15, lkb = (lane >> 4) * 16;
    const int p0 = blockIdx.x * 128;

    // stage
#pragma unroll
    for (int i = 0; i < 4; ++i) {
        int o = i * 8192 + tid * 16;
        int r = o >> 8;
        int cbs = (o & 255) ^ ((r & 7) << 4);
        async16((char*)Asb + i * 8192 + wid * 1024,
                (const char*)G + (size_t)(p0 + r) * 256 + cbs);
    }
#pragma unroll
    for (int i = 0; i < 8; ++i)
        async16((char*)Bsb + i * 8192 + wid * 1024,
                (const char*)wt2 + i * 8192 + tid * 16);
    async16((char*)W2ts + wid * 1024, (const char*)wt2h + tid * 16);
    for (int i = tid; i < 2048; i += 512) E1s[i] = E1[i];
    if (tid < 16) b2s[tid] = b2a[tid];
    else if (tid < 32) b2s[tid] = b2b[tid - 16];
    if (tid < 128) {
        int g = gtO[p0 + tid];
        gts[tid] = g & 15;
        gts[128 + tid] = g >> 4;
    }
    __syncthreads();

    // MFMA1: wave = rows RB..RB+31 x cols CB..CB+127 (one head per wave)
    const int RB = (wid >> 1) * 32, CB = (wid & 1) * 128;
    f32x4 acc[2][8];
#pragma unroll
    for (int m = 0; m < 2; ++m)
#pragma unroll
        for (int n = 0; n < 8; ++n) acc[m][n] = f32x4{0.f, 0.f, 0.f, 0.f};
    __builtin_amdgcn_s_setprio(1);
#pragma unroll
    for (int kk = 0; kk < 4; ++kk) {
        bf16x8 av[2], bv[8];
#pragma unroll
        for (int m = 0; m < 2; ++m) {
            int row = RB + m * 16 + lrow;
            int cb = (kk * 64 + lkb) ^ ((row & 7) << 4);
            av[m] = *(const bf16x8*)((const char*)Asb + row * 256 + cb);
        }
#pragma unroll
        for (int n = 0; n < 8; ++n) {
            int drow = CB + n * 16 + lrow;
            int cb = (kk * 64 + lkb) ^ ((drow & 7) << 4);
            bv[n] = *(const bf16x8*)((const char*)Bsb + drow * 256 + cb);
        }
#pragma unroll
        for (int m = 0; m < 2; ++m)
#pragma unroll
            for (int n = 0; n < 8; ++n)
                acc[m][n] = __builtin_amdgcn_mfma_f32_16x16x32_bf16(
                    av[m], bv[n], acc[m][n], 0, 0, 0);
    }
    __builtin_amdgcn_s_setprio(0);
    __syncthreads();  // everyone done reading A/B -> H may overwrite

    // epilogue -> H (bf16, swizzled rows of 512B)
    const float* b1p = CB ? b1b : b1a;
    float b1v[8];
#pragma unroll
    for (int n = 0; n < 8; ++n) b1v[n] = b1p[n * 16 + lrow];
#pragma unroll
    for (int m = 0; m < 2; ++m) {
#pragma unroll
        for (int q = 0; q < 4; ++q) {
            int p = RB + m * 16 + (lane >> 4) * 4 + q;
#pragma unroll
            for (int n = 0; n < 8; ++n) {
                float v = acc[m][n][q] + b1v[n];
                if (CB) v += E1s[gts[p] * 128 + n * 16 + lrow];
                v = v > 0.f ? v : 0.f;
                int colb = (CB + n * 16 + lrow) * 2;
                *(u16*)(Hb + p * 512 + (colb ^ ((p & 7) << 4))) = f2bf(v);
            }
        }
    }
    __syncthreads();

    // MFMA2: wave = rows RB2..RB2+15, both heads (K=128)
    const int RB2 = wid * 16;
    f32x4 acc2[2];
    acc2[0] = f32x4{0.f, 0.f, 0.f, 0.f};
    acc2[1] = f32x4{0.f, 0.f, 0.f, 0.f};
#pragma unroll
    for (int kk = 0; kk < 4; ++kk) {
        int row = RB2 + lrow;
        int cb = (kk * 64 + lkb) ^ ((row & 7) << 4);
        int cbw = (kk * 64 + lkb) ^ ((lrow & 7) << 4);
#pragma unroll
        for (int h = 0; h < 2; ++h) {
            bf16x8 a2 = *(const bf16x8*)(Hb + row * 512 + h * 256 + cb);
            bf16x8 b2v = *(const bf16x8*)((const char*)W2ts + h * 4096 +
                                          lrow * 256 + cbw);
            acc2[h] = __builtin_amdgcn_mfma_f32_16x16x32_bf16(a2, b2v, acc2[h],
                                                              0, 0, 0);
        }
    }
    // softmax(16 lanes) + entropy gather
    const int jj = lrow;
#pragma unroll
    for (int h = 0; h < 2; ++h) {
#pragma unroll
        for (int q = 0; q < 4; ++q) {
            int pt = RB2 + (lane >> 4) * 4 + q;
            float v = acc2[h][q] + b2s[h * 16 + jj];
            float mx = v;
#pragma unroll
            for (int o = 1; o < 16; o <<= 1) mx = fmaxf(mx, __shfl_xor(mx, o, 16));
            float e = expf(v - mx);
            float s = e;
#pragma unroll
            for (int o = 1; o < 16; o <<= 1) s += __shfl_xor(s, o, 16);
            float bits = -log2f(e / s + 1e-10f);
            bits = fminf(fmaxf(bits, 0.f), 50.f);
            if (jj == gts[h * 128 + pt]) bitsS[h * 128 + pt] = bits;
        }
    }
    __syncthreads();
    if (tid < 64) {
        float s = bitsS[tid] + bitsS[tid + 64] + bitsS[tid + 128] + bitsS[tid + 192];
#pragma unroll
        for (int o = 32; o > 0; o >>= 1) s += __shfl_down(s, o, 64);
        if (tid == 0) partial[blockIdx.x] = s;
    }
}

__global__ __launch_bounds__(256) void finalize_k(const float* __restrict__ partial,
                                                  float* __restrict__ out, int n) {
    float s = 0.f;
    for (int i = threadIdx.x; i < n; i += 256) s += partial[i];
#pragma unroll
    for (int o = 32; o > 0; o >>= 1) s += __shfl_down(s, o, 64);
    __shared__ float wsum[4];
    if ((threadIdx.x & 63) == 0) wsum[threadIdx.x >> 6] = s;
    __syncthreads();
    if (threadIdx.x == 0)
        out[0] = (wsum[0] + wsum[1] + wsum[2] + wsum[3]) * (1.0f / 4096.0f);
}

// ---------------------------------------------------------------------------
extern "C" void kernel_launch(void* const* d_in, const int* in_sizes, int n_in,
                              void* d_out, int out_size, void* d_ws,
                              size_t ws_size, hipStream_t stream) {
    const int N = 4096, M = 32768;
    const int* x_O = (const int*)d_in[0];
    const int* gt_O = (const int*)d_in[1];
    const int* nbr_par = (const int*)d_in[2];
    const int* nbr_ch = (const int*)d_in[3];
    const int* child_oct = (const int*)d_in[4];
    const float* prior_emb = (const float*)d_in[5];
    const float* convW[10] = {
        (const float*)d_in[6],  (const float*)d_in[7],  (const float*)d_in[8],
        (const float*)d_in[9],  (const float*)d_in[10], (const float*)d_in[12],
        (const float*)d_in[13], (const float*)d_in[14], (const float*)d_in[15],
        (const float*)d_in[16]};
    const float* oct_emb = (const float*)d_in[11];
    const float* s1_emb = (const float*)d_in[17];
    const float* h0W1 = (const float*)d_in[18];
    const float* h0b1 = (const float*)d_in[19];
    const float* h0W2 = (const float*)d_in[20];
    const float* h0b2 = (const float*)d_in[21];
    const float* h1W1 = (const float*)d_in[22];
    const float* h1b1 = (const float*)d_in[23];
    const float* h1W2 = (const float*)d_in[24];
    const float* h1b2 = (const float*)d_in[25];

    char* ws = (char*)d_ws;
    size_t off = 0;
    auto alloc = [&](size_t b) {
        void* p = ws + off;
        off += (b + 255) & ~(size_t)255;
        return p;
    };
    PrepArgs pa;
    for (int i = 0; i < 10; ++i) {
        pa.ws[i] = convW[i];
        pa.wd[i] = (u16*)alloc(27 * 128 * 128 * 2);
    }
    u16* Wt2 = (u16*)alloc(256 * 128 * 2);
    pa.ws[10] = h0W1;
    pa.ws[11] = h1W1;
    pa.wd[10] = Wt2;
    pa.wd[11] = Wt2 + 128 * 128;
    u16* wt2h = (u16*)alloc(2 * 16 * 128 * 2);
    float* E1 = (float*)alloc(16 * 128 * 4);
    pa.h0W2 = h0W2;
    pa.h1W2 = h1W2;
    pa.wt2h = wt2h;
    pa.s1emb = s1_emb;
    pa.h1W1f = h1W1;
    pa.E1 = E1;

    u16* fA = (u16*)alloc((size_t)N * 256);
    u16* fB = (u16*)alloc((size_t)N * 256);
    u16* fC = (u16*)alloc((size_t)N * 256);
    u16* gA = (u16*)alloc((size_t)M * 256);
    u16* gB = (u16*)alloc((size_t)M * 256);
    u16* gC = (u16*)alloc((size_t)M * 256);
    float* partial = (float*)alloc(256 * 4);

    prep_mega<<<554, 256, 0, stream>>>(pa);
    embed_k<<<N * 128 / 256, 256, 0, stream>>>(x_O, prior_emb, fA);

    // parent stack (full-K, BM=32, 128 blocks)
    conv_pipe<32><<<N / 32, 512, 0, stream>>>(fA, nbr_par, pa.wd[0], nullptr, fB);
    conv_pipe<32><<<N / 32, 512, 0, stream>>>(fB, nbr_par, pa.wd[1], nullptr, fC);
    conv_pipe<32><<<N / 32, 512, 0, stream>>>(fC, nbr_par, pa.wd[2], fB, fA);
    conv_pipe<32><<<N / 32, 512, 0, stream>>>(fA, nbr_par, pa.wd[3], nullptr, fC);
    conv_pipe<32><<<N / 32, 512, 0, stream>>>(fC, nbr_par, pa.wd[4], fA, fB);

    // expand to children
    expand_k<<<M * 128 / 256, 256, 0, stream>>>(fB, child_oct, oct_emb, gA);

    // child stack (full-K, BM=128, 256 blocks)
    conv_pipe<128><<<M / 128, 512, 0, stream>>>(gA, nbr_ch, pa.wd[5], nullptr, gB);
    conv_pipe<128><<<M / 128, 512, 0, stream>>>(gB, nbr_ch, pa.wd[6], nullptr, gC);
    conv_pipe<128><<<M / 128, 512, 0, stream>>>(gC, nbr_ch, pa.wd[7], gB, gA);
    conv_pipe<128><<<M / 128, 512, 0, stream>>>(gA, nbr_ch, pa.wd[8], nullptr, gC);
    conv_pipe<128><<<M / 128, 512, 0, stream>>>(gC, nbr_ch, pa.wd[9], gA, gB);

    fused_heads<<<M / 128, 512, 0, stream>>>(gB, gt_O, Wt2, wt2h, h0b1, h1b1,
                                             E1, h0b2, h1b2, partial);
    finalize_k<<<1, 256, 0, stream>>>(partial, (float*)d_out, 256);

    (void)in_sizes; (void)n_in; (void)out_size; (void)ws_size;
}

// Round 4
// 339.557 us; speedup vs baseline: 1.3063x; 1.3063x over previous
//
#include <hip/hip_runtime.h>

typedef unsigned int u32;
typedef unsigned short u16;
typedef short bf16x8 __attribute__((ext_vector_type(8)));
typedef float f32x4 __attribute__((ext_vector_type(4)));
typedef unsigned short u16x4 __attribute__((ext_vector_type(4)));

#define KOFF 27

__device__ __forceinline__ float bf2f(u16 u) {
    u32 x = ((u32)u) << 16;
    return __builtin_bit_cast(float, x);
}
__device__ __forceinline__ u16 f2bf(float f) {
    u32 u = __builtin_bit_cast(u32, f);
    u32 r = (u + 0x7FFFu + ((u >> 16) & 1u)) >> 16;  // RNE
    return (u16)r;
}
__device__ __forceinline__ void async16(void* lds, const void* g) {
    __builtin_amdgcn_global_load_lds(
        (const __attribute__((address_space(1))) u32*)g,
        (__attribute__((address_space(3))) u32*)lds, 16, 0, 0);
}

// ---------------------------------------------------------------------------
// Mega prep: all weight transposes + head tables in ONE launch.
//  blocks 0..539  : 10 conv weights, W[k][c][d] f32 -> bf16 Wt[k][d][c^sw]
//  blocks 540..543: h0W1/h1W1 -> Wt2[256][128] bf16 swizzled (head L1 concat)
//  blocks 544..545: h0W2/h1W2 [128][16] f32 -> wt2h [2][16][128] bf16 swizzled
//  blocks 546..553: E1[16][128] = s1emb @ h1W1 (fp32, exact)
// ---------------------------------------------------------------------------
struct PrepArgs {
    const float* ws[12];  // 10 conv W + h0W1 + h1W1
    u16* wd[12];          // 10 conv Wt + Wt2 rows 0..127 + Wt2 rows 128..255
    const float* h0W2;
    const float* h1W2;
    u16* wt2h;
    const float* s1emb;
    const float* h1W1f;
    float* E1;
};
__global__ __launch_bounds__(256) void prep_mega(PrepArgs a) {
    __shared__ float t[128][65];
    const int bid = blockIdx.x;
    if (bid < 544) {
        int w, k, half;
        if (bid < 540) {
            w = bid / 54;
            int r = bid % 54;
            k = r >> 1;
            half = r & 1;
        } else {
            int r = bid - 540;
            w = 10 + (r >> 1);
            k = 0;
            half = r & 1;
        }
        const float* s = a.ws[w] + k * 16384 + half * 64;
        for (int i = threadIdx.x; i < 8192; i += 256) {
            int c = i >> 6, dl = i & 63;
            t[c][dl] = s[c * 128 + dl];
        }
        __syncthreads();
        u16* db = a.wd[w] + k * 16384;
        for (int i = threadIdx.x; i < 8192; i += 256) {
            int dl = i >> 7, c = i & 127;
            int d = half * 64 + dl;
            db[d * 128 + (c ^ ((d & 7) << 3))] = f2bf(t[c][dl]);
        }
    } else if (bid < 546) {
        int h = bid - 544;
        const float* src = h ? a.h1W2 : a.h0W2;
        u16* dst = a.wt2h + h * 2048;
        for (int i = threadIdx.x; i < 2048; i += 256) {
            int j = i >> 7, d = i & 127;
            dst[j * 128 + (d ^ ((j & 7) << 3))] = f2bf(src[d * 16 + j]);
        }
    } else {
        int b = bid - 546;  // 0..7
        int r = b * 2 + (threadIdx.x >> 7);
        int c = threadIdx.x & 127;
        float acc = 0.f;
        for (int kx = 0; kx < 128; ++kx)
            acc = fmaf(a.s1emb[r * 128 + kx], a.h1W1f[kx * 128 + c], acc);
        a.E1[r * 128 + c] = acc;
    }
}

// f0[n][c] = prior_emb[x_O[n]][c]  (fp32 -> bf16)
__global__ __launch_bounds__(256) void embed_k(const int* __restrict__ xO,
                                               const float* __restrict__ emb,
                                               u16* __restrict__ out) {
    int idx = blockIdx.x * 256 + threadIdx.x;
    int c = idx & 127, n = idx >> 7;
    out[idx] = f2bf(emb[xO[n] * 128 + c]);
}

// g[m][c] = f[m>>3][c] + oct_emb[child_oct[m]][c]
__global__ __launch_bounds__(256) void expand_k(const u16* __restrict__ f,
                                                const int* __restrict__ oct,
                                                const float* __restrict__ oemb,
                                                u16* __restrict__ g) {
    int idx = blockIdx.x * 256 + threadIdx.x;
    int c = idx & 127, m = idx >> 7;
    g[idx] = f2bf(bf2f(f[(m >> 3) * 128 + c]) + oemb[oct[m] * 128 + c]);
}

// ---------------------------------------------------------------------------
// Sparse conv v2: BM=64 points/block, 256 threads (4 waves, each 32x64 tile).
// A double-buffered (gathered), B single-buffered (linear, pre-swizzled);
// LDS = 32K(A) + 32K(B) + 7K(nbr) = 71KB -> 2 blocks/CU (independent
// pipelines fill each other's stage/vmcnt bubbles).
// Per-thread VMEM stream per offset: [A(k) 4][B(k) 8][A(k+1) 4] -> vmcnt(4)
// guarantees A(k),B(k) landed with A(k+1) still in flight.
// PARTIAL: split-K over 8 offset groups (blockIdx.y), fp32 partials.
// Swizzle: byte-in-row ^= (row&7)<<4 on staged source and read.
// ---------------------------------------------------------------------------
template <bool PARTIAL>
__global__ __launch_bounds__(256, 2) void conv2(
    const u16* __restrict__ fin, const int* __restrict__ nbr,
    const u16* __restrict__ wt, const u16* __restrict__ res,
    u16* __restrict__ fout, float* __restrict__ pout, int npts) {
    constexpr int BM = 64;
    __shared__ __align__(16) u16 Asb[2][BM * 128];
    __shared__ __align__(16) u16 Bsb[128 * 128];
    __shared__ int nbrS[BM * KOFF];
    const int tid = threadIdx.x;
    const int wid = tid >> 6;
    const int lane = tid & 63;
    const int p0 = blockIdx.x * BM;
    const int g = PARTIAL ? blockIdx.y : 0;
    const int k0 = PARTIAL ? (g * KOFF) >> 3 : 0;
    const int k1 = PARTIAL ? ((g + 1) * KOFF) >> 3 : KOFF;

    for (int i = tid; i < BM * KOFF; i += 256)
        nbrS[i] = nbr[(p0 + i / KOFF) * KOFF + (i % KOFF)];
    __syncthreads();  // full drain: vmcnt==0 past this point

    f32x4 acc[2][4];
#pragma unroll
    for (int m = 0; m < 2; ++m)
#pragma unroll
        for (int n = 0; n < 4; ++n) acc[m][n] = f32x4{0.f, 0.f, 0.f, 0.f};

    const int RB = (wid >> 1) * 32;  // 2 row groups
    const int CB = (wid & 1) * 64;   // 2 col groups
    const int lrow = lane & 15;
    const int lkb = (lane >> 4) * 16;

    auto stageA = [&](int k, int buf) {
#pragma unroll
        for (int i = 0; i < 4; ++i) {
            int o = i * 4096 + tid * 16;
            int r = o >> 8;
            int cbs = (o & 255) ^ ((r & 7) << 4);
            int rg = nbrS[r * KOFF + k];
            async16((char*)&Asb[buf][0] + i * 4096 + wid * 1024,
                    (const char*)fin + (size_t)rg * 256 + cbs);
        }
    };
    auto stageB = [&](int k) {
        const char* wk = (const char*)wt + k * 32768;
#pragma unroll
        for (int i = 0; i < 8; ++i)
            async16((char*)&Bsb[0] + i * 4096 + wid * 1024,
                    wk + i * 4096 + tid * 16);
    };

    stageA(k0, 0);
    int cur = 0;
#pragma unroll 1
    for (int k = k0; k < k1; ++k) {
        __builtin_amdgcn_s_barrier();  // all waves done reading B[k-1]/A[k-1]
        stageB(k);
        if (k + 1 < k1) {
            stageA(k + 1, cur ^ 1);
            asm volatile("s_waitcnt vmcnt(4)" ::: "memory");  // A(k),B(k) done
        } else {
            asm volatile("s_waitcnt vmcnt(0)" ::: "memory");
        }
        __builtin_amdgcn_s_barrier();       // staged data visible to all waves
        __builtin_amdgcn_sched_barrier(0);  // no ds_read hoisting above
        __builtin_amdgcn_s_setprio(1);
#pragma unroll
        for (int kk = 0; kk < 4; ++kk) {
            bf16x8 av[2], bv[4];
#pragma unroll
            for (int m = 0; m < 2; ++m) {
                int row = RB + m * 16 + lrow;
                int cb = (kk * 64 + lkb) ^ ((row & 7) << 4);
                av[m] = *(const bf16x8*)((const char*)&Asb[cur][0] + row * 256 + cb);
            }
#pragma unroll
            for (int n = 0; n < 4; ++n) {
                int drow = CB + n * 16 + lrow;
                int cb = (kk * 64 + lkb) ^ ((drow & 7) << 4);
                bv[n] = *(const bf16x8*)((const char*)&Bsb[0] + drow * 256 + cb);
            }
#pragma unroll
            for (int m = 0; m < 2; ++m)
#pragma unroll
                for (int n = 0; n < 4; ++n)
                    acc[m][n] = __builtin_amdgcn_mfma_f32_16x16x32_bf16(
                        av[m], bv[n], acc[m][n], 0, 0, 0);
        }
        __builtin_amdgcn_s_setprio(0);
        cur ^= 1;
    }

    // epilogue.  D layout: col=lane&15, row=(lane>>4)*4+q
    if constexpr (PARTIAL) {
        float* pg = pout + (size_t)g * npts * 128;
#pragma unroll
        for (int m = 0; m < 2; ++m) {
            int prow = p0 + RB + m * 16 + (lane >> 4) * 4;
#pragma unroll
            for (int n = 0; n < 4; ++n) {
                int dcol = CB + n * 16 + lrow;
#pragma unroll
                for (int q = 0; q < 4; ++q)
                    pg[(prow + q) * 128 + dcol] = acc[m][n][q];
            }
        }
    } else {
#pragma unroll
        for (int m = 0; m < 2; ++m) {
            int prow = p0 + RB + m * 16 + (lane >> 4) * 4;
#pragma unroll
            for (int n = 0; n < 4; ++n) {
                int dcol = CB + n * 16 + lrow;
#pragma unroll
                for (int q = 0; q < 4; ++q) {
                    float v = acc[m][n][q];
                    int p = prow + q;
                    if (res) v += bf2f(res[p * 128 + dcol]);
                    v = v > 0.f ? v : 0.f;
                    fout[p * 128 + dcol] = f2bf(v);
                }
            }
        }
    }
}

// combine split-K partials: out = relu(sum_g P[g] (+ res)) -> bf16
__global__ __launch_bounds__(256) void combine_k(const float* __restrict__ P,
                                                 const u16* __restrict__ res,
                                                 u16* __restrict__ fout,
                                                 int nelem) {
    int base = (blockIdx.x * 256 + threadIdx.x) * 4;
    f32x4 s = *(const f32x4*)(P + base);
#pragma unroll
    for (int gg = 1; gg < 8; ++gg)
        s += *(const f32x4*)(P + (size_t)gg * nelem + base);
    u16x4 o;
    if (res) {
        u16x4 rv = *(const u16x4*)(res + base);
#pragma unroll
        for (int j = 0; j < 4; ++j) s[j] += bf2f(rv[j]);
    }
#pragma unroll
    for (int j = 0; j < 4; ++j) {
        float v = s[j] > 0.f ? s[j] : 0.f;
        o[j] = f2bf(v);
    }
    *(u16x4*)(fout + base) = o;
}

// ---------------------------------------------------------------------------
// Fused heads: one block = 128 points.
//  MFMA1: Hcat[128][256] = relu(G@[W1a|W1b] + b1 (+E1[gt0] for head1 cols))
//  MFMA2: logits[128][16] per head; softmax(16) + gathered -log2 + partial.
// ---------------------------------------------------------------------------
__global__ __launch_bounds__(512, 1) void fused_heads(
    const u16* __restrict__ G, const int* __restrict__ gtO,
    const u16* __restrict__ wt2, const u16* __restrict__ wt2h,
    const float* __restrict__ b1a, const float* __restrict__ b1b,
    const float* __restrict__ E1, const float* __restrict__ b2a,
    const float* __restrict__ b2b, float* __restrict__ partial) {
    __shared__ __align__(16) u16 AB[49152];   // 96KB: A 32K | B 64K
    __shared__ __align__(16) u16 W2ts[4096];  // 8KB: [2][16][128] swizzled
    __shared__ float E1s[2048];
    __shared__ float b2s[32];
    __shared__ int gts[256];
    __shared__ float bitsS[256];
    u16* Asb = AB;
    u16* Bsb = AB + 16384;
    char* Hb = (char*)AB;  // 128 rows x 512B, aliases A+B (dead after MFMA1)
    const int tid = threadIdx.x, wid = tid >> 6, lane = tid & 63;
    const int lrow = lane & 15, lkb = (lane >> 4) * 16;
    const int p0 = blockIdx.x * 128;

#pragma unroll
    for (int i = 0; i < 4; ++i) {
        int o = i * 8192 + tid * 16;
        int r = o >> 8;
        int cbs = (o & 255) ^ ((r & 7) << 4);
        async16((char*)Asb + i * 8192 + wid * 1024,
                (const char*)G + (size_t)(p0 + r) * 256 + cbs);
    }
#pragma unroll
    for (int i = 0; i < 8; ++i)
        async16((char*)Bsb + i * 8192 + wid * 1024,
                (const char*)wt2 + i * 8192 + tid * 16);
    async16((char*)W2ts + wid * 1024, (const char*)wt2h + tid * 16);
    for (int i = tid; i < 2048; i += 512) E1s[i] = E1[i];
    if (tid < 16) b2s[tid] = b2a[tid];
    else if (tid < 32) b2s[tid] = b2b[tid - 16];
    if (tid < 128) {
        int g = gtO[p0 + tid];
        gts[tid] = g & 15;
        gts[128 + tid] = g >> 4;
    }
    __syncthreads();

    const int RB = (wid >> 1) * 32, CB = (wid & 1) * 128;
    f32x4 acc[2][8];
#pragma unroll
    for (int m = 0; m < 2; ++m)
#pragma unroll
        for (int n = 0; n < 8; ++n) acc[m][n] = f32x4{0.f, 0.f, 0.f, 0.f};
    __builtin_amdgcn_s_setprio(1);
#pragma unroll
    for (int kk = 0; kk < 4; ++kk) {
        bf16x8 av[2], bv[8];
#pragma unroll
        for (int m = 0; m < 2; ++m) {
            int row = RB + m * 16 + lrow;
            int cb = (kk * 64 + lkb) ^ ((row & 7) << 4);
            av[m] = *(const bf16x8*)((const char*)Asb + row * 256 + cb);
        }
#pragma unroll
        for (int n = 0; n < 8; ++n) {
            int drow = CB + n * 16 + lrow;
            int cb = (kk * 64 + lkb) ^ ((drow & 7) << 4);
            bv[n] = *(const bf16x8*)((const char*)Bsb + drow * 256 + cb);
        }
#pragma unroll
        for (int m = 0; m < 2; ++m)
#pragma unroll
            for (int n = 0; n < 8; ++n)
                acc[m][n] = __builtin_amdgcn_mfma_f32_16x16x32_bf16(
                    av[m], bv[n], acc[m][n], 0, 0, 0);
    }
    __builtin_amdgcn_s_setprio(0);
    __syncthreads();  // everyone done reading A/B -> H may overwrite

    const float* b1p = CB ? b1b : b1a;
    float b1v[8];
#pragma unroll
    for (int n = 0; n < 8; ++n) b1v[n] = b1p[n * 16 + lrow];
#pragma unroll
    for (int m = 0; m < 2; ++m) {
#pragma unroll
        for (int q = 0; q < 4; ++q) {
            int p = RB + m * 16 + (lane >> 4) * 4 + q;
#pragma unroll
            for (int n = 0; n < 8; ++n) {
                float v = acc[m][n][q] + b1v[n];
                if (CB) v += E1s[gts[p] * 128 + n * 16 + lrow];
                v = v > 0.f ? v : 0.f;
                int colb = (CB + n * 16 + lrow) * 2;
                *(u16*)(Hb + p * 512 + (colb ^ ((p & 7) << 4))) = f2bf(v);
            }
        }
    }
    __syncthreads();

    const int RB2 = wid * 16;
    f32x4 acc2[2];
    acc2[0] = f32x4{0.f, 0.f, 0.f, 0.f};
    acc2[1] = f32x4{0.f, 0.f, 0.f, 0.f};
#pragma unroll
    for (int kk = 0; kk < 4; ++kk) {
        int row = RB2 + lrow;
        int cb = (kk * 64 + lkb) ^ ((row & 7) << 4);
        int cbw = (kk * 64 + lkb) ^ ((lrow & 7) << 4);
#pragma unroll
        for (int h = 0; h < 2; ++h) {
            bf16x8 a2 = *(const bf16x8*)(Hb + row * 512 + h * 256 + cb);
            bf16x8 b2v = *(const bf16x8*)((const char*)W2ts + h * 4096 +
                                          lrow * 256 + cbw);
            acc2[h] = __builtin_amdgcn_mfma_f32_16x16x32_bf16(a2, b2v, acc2[h],
                                                              0, 0, 0);
        }
    }
    const int jj = lrow;
#pragma unroll
    for (int h = 0; h < 2; ++h) {
#pragma unroll
        for (int q = 0; q < 4; ++q) {
            int pt = RB2 + (lane >> 4) * 4 + q;
            float v = acc2[h][q] + b2s[h * 16 + jj];
            float mx = v;
#pragma unroll
            for (int o = 1; o < 16; o <<= 1) mx = fmaxf(mx, __shfl_xor(mx, o, 16));
            float e = expf(v - mx);
            float s = e;
#pragma unroll
            for (int o = 1; o < 16; o <<= 1) s += __shfl_xor(s, o, 16);
            float bits = -log2f(e / s + 1e-10f);
            bits = fminf(fmaxf(bits, 0.f), 50.f);
            if (jj == gts[h * 128 + pt]) bitsS[h * 128 + pt] = bits;
        }
    }
    __syncthreads();
    if (tid < 64) {
        float s = bitsS[tid] + bitsS[tid + 64] + bitsS[tid + 128] + bitsS[tid + 192];
#pragma unroll
        for (int o = 32; o > 0; o >>= 1) s += __shfl_down(s, o, 64);
        if (tid == 0) partial[blockIdx.x] = s;
    }
}

__global__ __launch_bounds__(256) void finalize_k(const float* __restrict__ partial,
                                                  float* __restrict__ out, int n) {
    float s = 0.f;
    for (int i = threadIdx.x; i < n; i += 256) s += partial[i];
#pragma unroll
    for (int o = 32; o > 0; o >>= 1) s += __shfl_down(s, o, 64);
    __shared__ float wsum[4];
    if ((threadIdx.x & 63) == 0) wsum[threadIdx.x >> 6] = s;
    __syncthreads();
    if (threadIdx.x == 0)
        out[0] = (wsum[0] + wsum[1] + wsum[2] + wsum[3]) * (1.0f / 4096.0f);
}

// ---------------------------------------------------------------------------
extern "C" void kernel_launch(void* const* d_in, const int* in_sizes, int n_in,
                              void* d_out, int out_size, void* d_ws,
                              size_t ws_size, hipStream_t stream) {
    const int N = 4096, M = 32768;
    const int* x_O = (const int*)d_in[0];
    const int* gt_O = (const int*)d_in[1];
    const int* nbr_par = (const int*)d_in[2];
    const int* nbr_ch = (const int*)d_in[3];
    const int* child_oct = (const int*)d_in[4];
    const float* prior_emb = (const float*)d_in[5];
    const float* convW[10] = {
        (const float*)d_in[6],  (const float*)d_in[7],  (const float*)d_in[8],
        (const float*)d_in[9],  (const float*)d_in[10], (const float*)d_in[12],
        (const float*)d_in[13], (const float*)d_in[14], (const float*)d_in[15],
        (const float*)d_in[16]};
    const float* oct_emb = (const float*)d_in[11];
    const float* s1_emb = (const float*)d_in[17];
    const float* h0W1 = (const float*)d_in[18];
    const float* h0b1 = (const float*)d_in[19];
    const float* h0W2 = (const float*)d_in[20];
    const float* h0b2 = (const float*)d_in[21];
    const float* h1W1 = (const float*)d_in[22];
    const float* h1b1 = (const float*)d_in[23];
    const float* h1W2 = (const float*)d_in[24];
    const float* h1b2 = (const float*)d_in[25];

    char* ws = (char*)d_ws;
    size_t off = 0;
    auto alloc = [&](size_t b) {
        void* p = ws + off;
        off += (b + 255) & ~(size_t)255;
        return p;
    };
    PrepArgs pa;
    for (int i = 0; i < 10; ++i) {
        pa.ws[i] = convW[i];
        pa.wd[i] = (u16*)alloc(27 * 128 * 128 * 2);
    }
    u16* Wt2 = (u16*)alloc(256 * 128 * 2);
    pa.ws[10] = h0W1;
    pa.ws[11] = h1W1;
    pa.wd[10] = Wt2;
    pa.wd[11] = Wt2 + 128 * 128;
    u16* wt2h = (u16*)alloc(2 * 16 * 128 * 2);
    float* E1 = (float*)alloc(16 * 128 * 4);
    pa.h0W2 = h0W2;
    pa.h1W2 = h1W2;
    pa.wt2h = wt2h;
    pa.s1emb = s1_emb;
    pa.h1W1f = h1W1;
    pa.E1 = E1;

    u16* fA = (u16*)alloc((size_t)N * 256);
    u16* fB = (u16*)alloc((size_t)N * 256);
    u16* fC = (u16*)alloc((size_t)N * 256);
    u16* gA = (u16*)alloc((size_t)M * 256);
    u16* gB = (u16*)alloc((size_t)M * 256);
    u16* gC = (u16*)alloc((size_t)M * 256);
    float* partial = (float*)alloc(256 * 4);
    // split-K parent partials (8 * N * 128 fp32 = 16MB) alias gA (dead until
    // expand_k writes it after the parent stack completes).
    float* pconv = (float*)gA;

    prep_mega<<<554, 256, 0, stream>>>(pa);
    embed_k<<<N * 128 / 256, 256, 0, stream>>>(x_O, prior_emb, fA);

    const int PE = N * 128;
    // parent stack: split-K over 8 offset groups, grid (64,8)=512 blocks
    conv2<true><<<dim3(64, 8), 256, 0, stream>>>(fA, nbr_par, pa.wd[0], nullptr, nullptr, pconv, N);
    combine_k<<<PE / 1024, 256, 0, stream>>>(pconv, nullptr, fB, PE);
    conv2<true><<<dim3(64, 8), 256, 0, stream>>>(fB, nbr_par, pa.wd[1], nullptr, nullptr, pconv, N);
    combine_k<<<PE / 1024, 256, 0, stream>>>(pconv, nullptr, fC, PE);
    conv2<true><<<dim3(64, 8), 256, 0, stream>>>(fC, nbr_par, pa.wd[2], nullptr, nullptr, pconv, N);
    combine_k<<<PE / 1024, 256, 0, stream>>>(pconv, fB, fA, PE);
    conv2<true><<<dim3(64, 8), 256, 0, stream>>>(fA, nbr_par, pa.wd[3], nullptr, nullptr, pconv, N);
    combine_k<<<PE / 1024, 256, 0, stream>>>(pconv, nullptr, fC, PE);
    conv2<true><<<dim3(64, 8), 256, 0, stream>>>(fC, nbr_par, pa.wd[4], nullptr, nullptr, pconv, N);
    combine_k<<<PE / 1024, 256, 0, stream>>>(pconv, fA, fB, PE);

    // expand to children
    expand_k<<<M * 128 / 256, 256, 0, stream>>>(fB, child_oct, oct_emb, gA);

    // child stack: full-K, 512 blocks (2 per CU)
    conv2<false><<<dim3(512, 1), 256, 0, stream>>>(gA, nbr_ch, pa.wd[5], nullptr, gB, nullptr, M);
    conv2<false><<<dim3(512, 1), 256, 0, stream>>>(gB, nbr_ch, pa.wd[6], nullptr, gC, nullptr, M);
    conv2<false><<<dim3(512, 1), 256, 0, stream>>>(gC, nbr_ch, pa.wd[7], gB, gA, nullptr, M);
    conv2<false><<<dim3(512, 1), 256, 0, stream>>>(gA, nbr_ch, pa.wd[8], nullptr, gC, nullptr, M);
    conv2<false><<<dim3(512, 1), 256, 0, stream>>>(gC, nbr_ch, pa.wd[9], gA, gB, nullptr, M);

    fused_heads<<<M / 128, 512, 0, stream>>>(gB, gt_O, Wt2, wt2h, h0b1, h1b1,
                                             E1, h0b2, h1b2, partial);
    finalize_k<<<1, 256, 0, stream>>>(partial, (float*)d_out, 256);

    (void)in_sizes; (void)n_in; (void)out_size; (void)ws_size;
}